// Round 1
// baseline (1838.211 us; speedup 1.0000x reference)
//
#include <hip/hip_runtime.h>
#include <hip/hip_bf16.h>

typedef _Float16 half8_t __attribute__((ext_vector_type(8)));
typedef _Float16 half4_t __attribute__((ext_vector_type(4)));
typedef float float4_t __attribute__((ext_vector_type(4)));

#define TT 1024
#define BB 128
#define EE 128
#define HH 128
#define NTAG 64
#define ASTR 272  // padded LDS row stride (f16 elems): 544 B = 34 dwords -> ~2-way banks

__device__ __forceinline__ float fast_sigmoid(float x) {
  return __builtin_amdgcn_rcpf(1.0f + __builtin_amdgcn_exp2f(-1.44269504088896f * x));
}
__device__ __forceinline__ float fast_tanh(float x) {
  // tanh(x) = 1 - 2/(exp(2x)+1); saturates correctly for |x| large
  return 1.0f - 2.0f * __builtin_amdgcn_rcpf(1.0f + __builtin_amdgcn_exp2f(2.88539008177793f * x));
}
__device__ __forceinline__ float fast_exp(float x) {
  return __builtin_amdgcn_exp2f(x * 1.44269504088896f);
}

// ---------------------------------------------------------------- embed: x[t,b,:] = f16(emb[kmers[t,b]])
__global__ __launch_bounds__(256) void embed_kernel(const int* __restrict__ kmers,
                                                    const float* __restrict__ emb,
                                                    half4_t* __restrict__ x) {
  const int g = blockIdx.x * 256 + threadIdx.x;  // T*B*32 threads
  const int row = g >> 5, seg = g & 31;
  const int km = kmers[row];
  const float4_t v = ((const float4_t*)(emb + (size_t)km * EE))[seg];
  half4_t o;
  o[0] = (_Float16)v[0]; o[1] = (_Float16)v[1];
  o[2] = (_Float16)v[2]; o[3] = (_Float16)v[3];
  x[(size_t)row * 32 + seg] = o;
}

// ---------------------------------------------------------------- bidirectional LSTM
// grid 16: wg = dir*8 + chunk, each wg owns 16 batches, loops all T steps.
// A-panel (LDS, double buffered): [16 batches][256 = x|h] f16. Weights in regs.
__global__ __launch_bounds__(512, 2) void lstm_kernel(
    const half4_t* __restrict__ x,
    const float* __restrict__ w_ih_f, const float* __restrict__ w_hh_f,
    const float* __restrict__ b_ih_f, const float* __restrict__ b_hh_f,
    const float* __restrict__ w_ih_b, const float* __restrict__ w_hh_b,
    const float* __restrict__ b_ih_b, const float* __restrict__ b_hh_b,
    _Float16* __restrict__ h_cat) {
  __shared__ _Float16 A[2][16 * ASTR];
  const int wg = blockIdx.x;
  const int dir = wg >> 3;
  const int b0 = (wg & 7) * 16;
  const float* w_ih = dir ? w_ih_b : w_ih_f;
  const float* w_hh = dir ? w_hh_b : w_hh_f;
  const float* b_ih = dir ? b_ih_b : b_ih_f;
  const float* b_hh = dir ? b_hh_b : b_hh_f;

  const int tid = threadIdx.x;
  const int wave = tid >> 6, lane = tid & 63;
  const int n16 = lane & 15, quad = lane >> 4;
  const int hu = wave * 16 + n16;  // hidden unit this lane's B-frags cover

  // B-operand frags: B[k][n] = W[n][k]; lane holds W[n_global][kf*32+quad*8 .. +7]
  half8_t bf[4][8];
#pragma unroll
  for (int g = 0; g < 4; ++g) {
    const int ng = g * HH + hu;  // gate-row in [4H]
#pragma unroll
    for (int kf = 0; kf < 8; ++kf) {
      const int kb = kf * 32 + quad * 8;
      const float* src = (kb < EE) ? (w_ih + ng * EE + kb) : (w_hh + ng * HH + (kb - EE));
#pragma unroll
      for (int j = 0; j < 8; ++j) bf[g][kf][j] = (_Float16)src[j];
    }
  }
  float bias[4];
#pragma unroll
  for (int g = 0; g < 4; ++g) bias[g] = b_ih[g * HH + hu] + b_hh[g * HH + hu];

  // zero both A buffers (h region must start at 0)
  {
    _Float16* Af = &A[0][0];
    for (int i = tid; i < 2 * 16 * ASTR; i += 512) Af[i] = (_Float16)0.0f;
  }
  __syncthreads();
  const int xrow = tid >> 5, xseg = tid & 31;
  {  // load x_0 into buffer 0
    const int t0 = dir ? (TT - 1) : 0;
    half4_t v = x[((size_t)t0 * BB + b0 + xrow) * 32 + xseg];
    *(half4_t*)(&A[0][xrow * ASTR + xseg * 4]) = v;
  }

  float c[4] = {0.f, 0.f, 0.f, 0.f};

  for (int t = 0; t < TT; ++t) {
    // prefetch x_{t+1} (global -> regs) before the barrier
    half4_t xv = {};
    const bool hasx = (t + 1 < TT);
    if (hasx) {
      const int tn = dir ? (TT - 2 - t) : (t + 1);
      xv = x[((size_t)tn * BB + b0 + xrow) * 32 + xseg];
    }
    __syncthreads();  // buf[t&1] (x_t + h_{t-1}) fully written
    const _Float16* Ab = &A[t & 1][0];
    _Float16* An = &A[(t + 1) & 1][0];

    float4_t acc[4];
#pragma unroll
    for (int g = 0; g < 4; ++g) acc[g] = (float4_t){bias[g], bias[g], bias[g], bias[g]};
#pragma unroll
    for (int kf = 0; kf < 8; ++kf) {
      half8_t af = *(const half8_t*)(Ab + n16 * ASTR + kf * 32 + quad * 8);
#pragma unroll
      for (int g = 0; g < 4; ++g)
        acc[g] = __builtin_amdgcn_mfma_f32_16x16x32_f16(af, bf[g][kf], acc[g], 0, 0, 0);
    }
    // stage x_{t+1} into the other buffer (no sync needed: prior readers done at barrier)
    if (hasx) *(half4_t*)(An + xrow * ASTR + xseg * 4) = xv;

    const int te = dir ? (TT - 1 - t) : t;
    _Float16* gptr = h_cat + ((size_t)te * BB + b0 + quad * 4) * 256 + dir * HH + hu;
#pragma unroll
    for (int r = 0; r < 4; ++r) {
      const float gi = acc[0][r], gf = acc[1][r], gg = acc[2][r], go = acc[3][r];
      const float cr = fast_sigmoid(gf) * c[r] + fast_sigmoid(gi) * fast_tanh(gg);
      c[r] = cr;
      const float hv = fast_sigmoid(go) * fast_tanh(cr);
      const _Float16 hh = (_Float16)hv;
      An[(quad * 4 + r) * ASTR + EE + hu] = hh;  // h_t for next step
      gptr[r * 256] = hh;                        // h_cat[te][b][dir*128+hu]
    }
  }
}

// ---------------------------------------------------------------- emissions: em = h_cat @ w_proj^T + b_proj
__global__ __launch_bounds__(256) void emis_kernel(const _Float16* __restrict__ h_cat,
                                                   const float* __restrict__ w_proj,
                                                   const float* __restrict__ b_proj,
                                                   float* __restrict__ em) {
  const int tid = threadIdx.x;
  const int wave = tid >> 6, lane = tid & 63;
  const int n16 = lane & 15, quad = lane >> 4;
  const size_t row0 = (size_t)blockIdx.x * 64 + wave * 16;

  half8_t bf[4][8];
#pragma unroll
  for (int nt = 0; nt < 4; ++nt) {
    const float* wp = w_proj + (nt * 16 + n16) * 256;
#pragma unroll
    for (int kf = 0; kf < 8; ++kf) {
      const int kb = kf * 32 + quad * 8;
#pragma unroll
      for (int i = 0; i < 8; ++i) bf[nt][kf][i] = (_Float16)wp[kb + i];
    }
  }
  float4_t acc[4];
#pragma unroll
  for (int nt = 0; nt < 4; ++nt) {
    const float bv = b_proj[nt * 16 + n16];
    acc[nt] = (float4_t){bv, bv, bv, bv};
  }
#pragma unroll
  for (int kf = 0; kf < 8; ++kf) {
    half8_t af = *(const half8_t*)(h_cat + (row0 + n16) * 256 + kf * 32 + quad * 8);
#pragma unroll
    for (int nt = 0; nt < 4; ++nt)
      acc[nt] = __builtin_amdgcn_mfma_f32_16x16x32_f16(af, bf[nt][kf], acc[nt], 0, 0, 0);
  }
#pragma unroll
  for (int nt = 0; nt < 4; ++nt)
#pragma unroll
    for (int r = 0; r < 4; ++r)
      em[(row0 + quad * 4 + r) * NTAG + nt * 16 + n16] = acc[nt][r];
}

// ---------------------------------------------------------------- CRF forward (log-partition)
// score'[b,j] = m_b + ln( sum_k exp(score[b,k]-m_b) * exp(trans[k,j]) ) + em[t,b,j]
__global__ __launch_bounds__(256) void crf_kernel(const float* __restrict__ em,
                                                  const float* __restrict__ trans,
                                                  const float* __restrict__ start_trans,
                                                  const float* __restrict__ end_trans,
                                                  float* __restrict__ denom) {
  const int b0 = blockIdx.x * 16;
  const int tid = threadIdx.x;
  const int wave = tid >> 6, lane = tid & 63;
  const int n16 = lane & 15, quad = lane >> 4;
  const int j = wave * 16 + n16;

  // E = exp(trans) as constant B-operand frags (K=64 -> 2 kfrags)
  half8_t ef[2];
#pragma unroll
  for (int kf = 0; kf < 2; ++kf)
#pragma unroll
    for (int i = 0; i < 8; ++i)
      ef[kf][i] = (_Float16)fast_exp(trans[(kf * 32 + quad * 8 + i) * NTAG + j]);

  __shared__ _Float16 p_lds[16][72];
  __shared__ __align__(16) float pmax[16][4];
  __shared__ __align__(16) float psum[16][4];

  float s[4];
#pragma unroll
  for (int r = 0; r < 4; ++r)
    s[r] = start_trans[j] + em[(size_t)(b0 + quad * 4 + r) * NTAG + j];

  for (int t = 1; t < TT; ++t) {
    float emr[4];
#pragma unroll
    for (int r = 0; r < 4; ++r)
      emr[r] = em[((size_t)t * BB + b0 + quad * 4 + r) * NTAG + j];

    // global (over all 64 j) per-batch max
    float mx[4];
#pragma unroll
    for (int r = 0; r < 4; ++r) mx[r] = s[r];
#pragma unroll
    for (int off = 1; off < 16; off <<= 1)
#pragma unroll
      for (int r = 0; r < 4; ++r) mx[r] = fmaxf(mx[r], __shfl_xor(mx[r], off, 64));
    if (n16 == 0)
#pragma unroll
      for (int r = 0; r < 4; ++r) pmax[quad * 4 + r][wave] = mx[r];
    __syncthreads();
    float m[4];
#pragma unroll
    for (int r = 0; r < 4; ++r) {
      float4_t pm = *(const float4_t*)pmax[quad * 4 + r];
      m[r] = fmaxf(fmaxf(pm[0], pm[1]), fmaxf(pm[2], pm[3]));
    }
    // p = exp(score - m), f16, into A-operand layout [batch][k=j]
#pragma unroll
    for (int r = 0; r < 4; ++r)
      p_lds[quad * 4 + r][j] = (_Float16)__builtin_amdgcn_exp2f((s[r] - m[r]) * 1.44269504088896f);
    __syncthreads();
    float4_t acc = (float4_t){0.f, 0.f, 0.f, 0.f};
#pragma unroll
    for (int kf = 0; kf < 2; ++kf) {
      half8_t af = *(const half8_t*)(&p_lds[n16][kf * 32 + quad * 8]);
      acc = __builtin_amdgcn_mfma_f32_16x16x32_f16(af, ef[kf], acc, 0, 0, 0);
    }
#pragma unroll
    for (int r = 0; r < 4; ++r)
      s[r] = m[r] + 0.693147180559945f * __builtin_amdgcn_logf(acc[r]) + emr[r];
  }

  // denominator = logsumexp_j(s + end_trans)
#pragma unroll
  for (int r = 0; r < 4; ++r) s[r] += end_trans[j];
  float mx[4];
#pragma unroll
  for (int r = 0; r < 4; ++r) mx[r] = s[r];
#pragma unroll
  for (int off = 1; off < 16; off <<= 1)
#pragma unroll
    for (int r = 0; r < 4; ++r) mx[r] = fmaxf(mx[r], __shfl_xor(mx[r], off, 64));
  if (n16 == 0)
#pragma unroll
    for (int r = 0; r < 4; ++r) pmax[quad * 4 + r][wave] = mx[r];
  __syncthreads();
  float m[4], pe[4];
#pragma unroll
  for (int r = 0; r < 4; ++r) {
    float4_t pm = *(const float4_t*)pmax[quad * 4 + r];
    m[r] = fmaxf(fmaxf(pm[0], pm[1]), fmaxf(pm[2], pm[3]));
    pe[r] = fast_exp(s[r] - m[r]);
  }
#pragma unroll
  for (int off = 1; off < 16; off <<= 1)
#pragma unroll
    for (int r = 0; r < 4; ++r) pe[r] += __shfl_xor(pe[r], off, 64);
  if (n16 == 0)
#pragma unroll
    for (int r = 0; r < 4; ++r) psum[quad * 4 + r][wave] = pe[r];
  __syncthreads();
  if (wave == 0 && n16 == 0) {
#pragma unroll
    for (int r = 0; r < 4; ++r) {
      float4_t ps = *(const float4_t*)psum[quad * 4 + r];
      denom[b0 + quad * 4 + r] =
          m[r] + 0.693147180559945f * __builtin_amdgcn_logf(ps[0] + ps[1] + ps[2] + ps[3]);
    }
  }
}

// ---------------------------------------------------------------- numerator (tags constant over time)
__global__ __launch_bounds__(256) void numer_kernel(const float* __restrict__ em,
                                                    const int* __restrict__ tags,
                                                    const float* __restrict__ trans,
                                                    const float* __restrict__ start_trans,
                                                    const float* __restrict__ end_trans,
                                                    float* __restrict__ num) {
  const int b = blockIdx.x;
  const int tg = tags[b];
  float acc = 0.f;
  for (int t = threadIdx.x; t < TT; t += 256)
    acc += em[((size_t)t * BB + b) * NTAG + tg];
#pragma unroll
  for (int off = 32; off > 0; off >>= 1) acc += __shfl_xor(acc, off, 64);
  __shared__ float red[4];
  if ((threadIdx.x & 63) == 0) red[threadIdx.x >> 6] = acc;
  __syncthreads();
  if (threadIdx.x == 0) {
    const float tot = red[0] + red[1] + red[2] + red[3];
    num[b] = start_trans[tg] + end_trans[tg] + 1023.0f * trans[tg * NTAG + tg] + tot;
  }
}

// ---------------------------------------------------------------- final: sum_b (denom - num)
__global__ __launch_bounds__(128) void final_kernel(const float* __restrict__ denom,
                                                    const float* __restrict__ num,
                                                    float* __restrict__ out) {
  const int tid = threadIdx.x;
  float v = denom[tid] - num[tid];
#pragma unroll
  for (int off = 32; off > 0; off >>= 1) v += __shfl_xor(v, off, 64);
  __shared__ float red[2];
  if ((tid & 63) == 0) red[tid >> 6] = v;
  __syncthreads();
  if (tid == 0) out[0] = red[0] + red[1];
}

extern "C" void kernel_launch(void* const* d_in, const int* in_sizes, int n_in,
                              void* d_out, int out_size, void* d_ws, size_t ws_size,
                              hipStream_t stream) {
  const int* kmers = (const int*)d_in[0];
  const int* tags = (const int*)d_in[1];
  const float* emb = (const float*)d_in[2];
  const float* w_ih_f = (const float*)d_in[3];
  const float* w_hh_f = (const float*)d_in[4];
  const float* b_ih_f = (const float*)d_in[5];
  const float* b_hh_f = (const float*)d_in[6];
  const float* w_ih_b = (const float*)d_in[7];
  const float* w_hh_b = (const float*)d_in[8];
  const float* b_ih_b = (const float*)d_in[9];
  const float* b_hh_b = (const float*)d_in[10];
  const float* w_proj = (const float*)d_in[11];
  const float* b_proj = (const float*)d_in[12];
  const float* start_trans = (const float*)d_in[13];
  const float* end_trans = (const float*)d_in[14];
  const float* trans = (const float*)d_in[15];

  char* ws = (char*)d_ws;
  half4_t* x = (half4_t*)ws;                     // T*B*E f16        = 33,554,432 B
  _Float16* h_cat = (_Float16*)(ws + 33554432);  // T*B*256 f16      = 67,108,864 B
  float* em = (float*)(ws + 100663296);          // T*B*64 f32       = 33,554,432 B
  float* denom = (float*)(ws + 134217728);       // 128 f32
  float* num = denom + 128;                      // 128 f32
  float* out = (float*)d_out;

  hipLaunchKernelGGL(embed_kernel, dim3(16384), dim3(256), 0, stream, kmers, emb, x);
  hipLaunchKernelGGL(lstm_kernel, dim3(16), dim3(512), 0, stream, x, w_ih_f, w_hh_f, b_ih_f,
                     b_hh_f, w_ih_b, w_hh_b, b_ih_b, b_hh_b, h_cat);
  hipLaunchKernelGGL(emis_kernel, dim3(2048), dim3(256), 0, stream, h_cat, w_proj, b_proj, em);
  hipLaunchKernelGGL(crf_kernel, dim3(8), dim3(256), 0, stream, em, trans, start_trans,
                     end_trans, denom);
  hipLaunchKernelGGL(numer_kernel, dim3(128), dim3(256), 0, stream, em, tags, trans, start_trans,
                     end_trans, num);
  hipLaunchKernelGGL(final_kernel, dim3(1), dim3(128), 0, stream, denom, num, out);
}